// Round 6
// baseline (1606.453 us; speedup 1.0000x reference)
//
#include <hip/hip_runtime.h>

#define NN 100000
#define NE 600000
#define HH 128
#define NL 5
#define BN_EPS 1e-5f
#define NB 391    // (NN+255)/256
#define GGB 2048  // gather grid blocks

typedef float f4 __attribute__((ext_vector_type(4)));
typedef float f2 __attribute__((ext_vector_type(2)));
typedef _Float16 h8 __attribute__((ext_vector_type(8)));
typedef _Float16 h2x __attribute__((ext_vector_type(2)));

// ---------------- edge-index dtype probe + normalize to int32 ----------------
__global__ void k_probe(const unsigned long long* __restrict__ e, int* __restrict__ flag) {
    if (blockIdx.x == 0 && threadIdx.x == 0) {
        int ok = 1;
        for (int i = 0; i < 64; ++i)
            if (e[i] >= (unsigned long long)NN) ok = 0;
        *flag = ok; // 1 => int64, 0 => int32
    }
}

__global__ void k_convert(const void* __restrict__ src, const int* __restrict__ flag,
                          int* __restrict__ dst) {
    int i = blockIdx.x * 256 + threadIdx.x;
    if (i >= 2 * NE) return;
    if (*flag) dst[i] = (int)((const long long*)src)[i];
    else       dst[i] = ((const int*)src)[i];
}

__global__ void k_zero(int* __restrict__ p, int n) {
    int i = blockIdx.x * 256 + threadIdx.x;
    if (i < n) p[i] = 0;
}

// ---------------- degree / dinv ----------------
__global__ void k_count_deg(const int* __restrict__ col, int* __restrict__ degi) {
    int e = blockIdx.x * 256 + threadIdx.x;
    if (e < NE) atomicAdd(&degi[col[e]], 1);
}

__global__ void k_dinv(const int* __restrict__ degi, float* __restrict__ dinv) {
    int i = blockIdx.x * 256 + threadIdx.x;
    if (i < NN) dinv[i] = rsqrtf((float)degi[i] + 1.0f);
}

// ---------------- prefix scan ----------------
__global__ __launch_bounds__(256) void k_scan1(const int* __restrict__ degi,
                                               int* __restrict__ incl,
                                               int* __restrict__ blocksums) {
    __shared__ int sd[256];
    int tid = threadIdx.x;
    int i = blockIdx.x * 256 + tid;
    int v = (i < NN) ? degi[i] : 0;
    sd[tid] = v;
    __syncthreads();
#pragma unroll
    for (int off = 1; off < 256; off <<= 1) {
        int t = (tid >= off) ? sd[tid - off] : 0;
        __syncthreads();
        sd[tid] += t;
        __syncthreads();
    }
    if (i < NN) incl[i] = sd[tid];
    if (tid == 255) blocksums[blockIdx.x] = sd[255];
}

__global__ __launch_bounds__(512) void k_scan2(const int* __restrict__ blocksums,
                                               int* __restrict__ blockoffs) {
    __shared__ int sd[512];
    int tid = threadIdx.x;
    int v = (tid < NB) ? blocksums[tid] : 0;
    sd[tid] = v;
    __syncthreads();
#pragma unroll
    for (int off = 1; off < 512; off <<= 1) {
        int t = (tid >= off) ? sd[tid - off] : 0;
        __syncthreads();
        sd[tid] += t;
        __syncthreads();
    }
    if (tid < NB) blockoffs[tid] = sd[tid] - v;
}

__global__ void k_scan3(const int* __restrict__ incl, const int* __restrict__ degi,
                        const int* __restrict__ blockoffs,
                        int* __restrict__ offsets, int* __restrict__ cursor) {
    int i = blockIdx.x * 256 + threadIdx.x;
    if (i >= NN) return;
    offsets[i] = incl[i] - degi[i] + blockoffs[blockIdx.x];
    cursor[i] = 0;
}

__global__ void k_scatter(const int* __restrict__ ei, const float* __restrict__ dinv,
                          const int* __restrict__ offsets, int* __restrict__ cursor,
                          int2* __restrict__ csr) {
    int e = blockIdx.x * 256 + threadIdx.x;
    if (e >= NE) return;
    int r = ei[e], c = ei[NE + e];
    int pos = offsets[c] + atomicAdd(&cursor[c], 1);
    int2 v;
    v.x = r;
    v.y = __float_as_int(dinv[r] * dinv[c]);
    csr[pos] = v;
}

// ---- transpose + split-cast weights: Wt{hi,lo}[l][n][k] from W[l][k][n] (fp32) ----
__global__ void k_wt(const float* __restrict__ W, _Float16* __restrict__ Wt_hi,
                     _Float16* __restrict__ Wt_lo) {
    int gid = blockIdx.x * 256 + threadIdx.x; // over NL*128*128
    if (gid >= NL * HH * HH) return;
    int l = gid >> 14;
    int rem = gid & 16383;
    int n = rem >> 7;
    int k = rem & 127;
    float w = W[l * HH * HH + k * HH + n];
    _Float16 hi = (_Float16)w;
    _Float16 lo = (_Float16)(w - (float)hi);
    Wt_hi[gid] = hi;
    Wt_lo[gid] = lo;
}

// ---- per-layer BN scale/shift: sc = gamma*rsqrt(var+eps), sh = beta-mean*sc ----
__global__ void k_prep(const float* __restrict__ stats, const float* __restrict__ gamma,
                       const float* __restrict__ beta, int mode, float* __restrict__ scsh) {
    int k = threadIdx.x; // 128 threads
    float sc = 1.0f, sh = 0.0f;
    if (mode) {
        const float inv_n = 1.0f / (float)NN;
        float mean = stats[k] * inv_n;
        float var  = stats[128 + k] * inv_n - mean * mean;
        sc = gamma[k] * rsqrtf(var + BN_EPS);
        sh = beta[k] - mean * sc;
    }
    scsh[k] = sc;
    scsh[128 + k] = sh;
}

// ---------------- fused GEMM: h1 = relu?(bn(A)) @ W, split-fp16 MFMA, fp32 I/O ------
// h1 = A_hi@W_hi + A_hi@W_lo + A_lo@W_hi  (error ~2^-22 rel; effectively fp32)
__global__ __launch_bounds__(256) void k_gemm(const float* __restrict__ A,
                                              const _Float16* __restrict__ Wt_hi,
                                              const _Float16* __restrict__ Wt_lo,
                                              const float* __restrict__ scsh,
                                              float negmul,
                                              float* __restrict__ C) {
    const int tid  = threadIdx.x;
    const int wave = tid >> 6;
    const int lane = tid & 63;
    const int r    = lane & 15;
    const int kg   = lane >> 4;        // 0..3
    const int row0 = blockIdx.x * 128 + wave * 32;

    f4 acc[2][8];
#pragma unroll
    for (int m = 0; m < 2; ++m)
#pragma unroll
        for (int n = 0; n < 8; ++n) acc[m][n] = (f4)0.0f;

    int ra0 = row0 + r;       if (ra0 >= NN) ra0 = NN - 1;
    int ra1 = row0 + 16 + r;  if (ra1 >= NN) ra1 = NN - 1;
    const float* A0 = A + (size_t)ra0 * HH + kg * 8;
    const float* A1 = A + (size_t)ra1 * HH + kg * 8;
    const _Float16* BpH = Wt_hi + (size_t)r * HH + kg * 8;  // + n*16*HH + kc*32
    const _Float16* BpL = Wt_lo + (size_t)r * HH + kg * 8;

#pragma unroll
    for (int kc = 0; kc < 4; ++kc) {
        const int k0 = kc * 32 + kg * 8;
        f4 scA = *reinterpret_cast<const f4*>(scsh + k0);
        f4 scB = *reinterpret_cast<const f4*>(scsh + k0 + 4);
        f4 shA = *reinterpret_cast<const f4*>(scsh + 128 + k0);
        f4 shB = *reinterpret_cast<const f4*>(scsh + 128 + k0 + 4);
        f4 a0x = *reinterpret_cast<const f4*>(A0 + kc * 32);
        f4 a0y = *reinterpret_cast<const f4*>(A0 + kc * 32 + 4);
        f4 a1x = *reinterpret_cast<const f4*>(A1 + kc * 32);
        f4 a1y = *reinterpret_cast<const f4*>(A1 + kc * 32 + 4);
        h8 a0hi, a0lo, a1hi, a1lo;
#pragma unroll
        for (int j = 0; j < 4; ++j) {
            float t;
            t = fmaf(a0x[j], scA[j], shA[j]); t = fmaxf(t, t * negmul);
            a0hi[j] = (_Float16)t;      a0lo[j] = (_Float16)(t - (float)a0hi[j]);
            t = fmaf(a0y[j], scB[j], shB[j]); t = fmaxf(t, t * negmul);
            a0hi[j + 4] = (_Float16)t;  a0lo[j + 4] = (_Float16)(t - (float)a0hi[j + 4]);
            t = fmaf(a1x[j], scA[j], shA[j]); t = fmaxf(t, t * negmul);
            a1hi[j] = (_Float16)t;      a1lo[j] = (_Float16)(t - (float)a1hi[j]);
            t = fmaf(a1y[j], scB[j], shB[j]); t = fmaxf(t, t * negmul);
            a1hi[j + 4] = (_Float16)t;  a1lo[j + 4] = (_Float16)(t - (float)a1hi[j + 4]);
        }
#pragma unroll
        for (int n = 0; n < 8; ++n) {
            h8 bh = *reinterpret_cast<const h8*>(BpH + (size_t)n * 16 * HH + kc * 32);
            h8 bl = *reinterpret_cast<const h8*>(BpL + (size_t)n * 16 * HH + kc * 32);
            acc[0][n] = __builtin_amdgcn_mfma_f32_16x16x32_f16(a0hi, bh, acc[0][n], 0, 0, 0);
            acc[0][n] = __builtin_amdgcn_mfma_f32_16x16x32_f16(a0hi, bl, acc[0][n], 0, 0, 0);
            acc[0][n] = __builtin_amdgcn_mfma_f32_16x16x32_f16(a0lo, bh, acc[0][n], 0, 0, 0);
            acc[1][n] = __builtin_amdgcn_mfma_f32_16x16x32_f16(a1hi, bh, acc[1][n], 0, 0, 0);
            acc[1][n] = __builtin_amdgcn_mfma_f32_16x16x32_f16(a1hi, bl, acc[1][n], 0, 0, 0);
            acc[1][n] = __builtin_amdgcn_mfma_f32_16x16x32_f16(a1lo, bh, acc[1][n], 0, 0, 0);
        }
    }

    // C/D: col=lane&15, row=(lane>>4)*4+reg  [m89-verified]
#pragma unroll
    for (int m = 0; m < 2; ++m) {
#pragma unroll
        for (int i = 0; i < 4; ++i) {
            int rr = row0 + m * 16 + kg * 4 + i;
            if (rr < NN) {
#pragma unroll
                for (int n = 0; n < 8; ++n)
                    C[(size_t)rr * HH + n * 16 + r] = acc[m][n][i];
            }
        }
    }
}

// ------- gather aggregation + fused BN stats (fp32) -------
// Wave per node (grid-stride): lanes hold f4 (32 lanes = 512B row); the wave's two
// 32-lane groups process different edges; 2-deep unroll => 4 row-loads in flight.
// Per-thread register accumulation of column sum/sumsq; one LDS reduce + 256 atomics
// per block at the end (replaces the separate k_bnstats pass).
__global__ __launch_bounds__(256) void k_gather(const float* __restrict__ h1,
                                                const int* __restrict__ offsets,
                                                const int* __restrict__ degi,
                                                const int2* __restrict__ csr,
                                                const float* __restrict__ dinv,
                                                float* __restrict__ h2,
                                                float* __restrict__ stats) {
    __shared__ f4 ls[4][32];
    __shared__ f4 lss[4][32];
    const int wid  = threadIdx.x >> 6;   // wave in block 0..3
    const int lane = threadIdx.x & 63;
    const int grp  = lane >> 5;          // 0/1
    const int l32  = lane & 31;
    const int stride = GGB * 4;

    f4 ssum = (f4)0.0f, ssq = (f4)0.0f;

    for (int node = blockIdx.x * 4 + wid; node < NN; node += stride) {
        float di = dinv[node];
        f4 acc = (f4)0.0f;
        if (grp == 0)
            acc = *reinterpret_cast<const f4*>(h1 + (size_t)node * HH + l32 * 4) * (di * di);
        const int start = offsets[node];
        const int end   = start + degi[node];
        int b = start + (grp << 1);
        while (b + 1 < end) {
            int2 ce0 = csr[b];
            int2 ce1 = csr[b + 1];
            f4 v0 = *reinterpret_cast<const f4*>(h1 + (size_t)ce0.x * HH + l32 * 4);
            f4 v1 = *reinterpret_cast<const f4*>(h1 + (size_t)ce1.x * HH + l32 * 4);
            acc += v0 * __int_as_float(ce0.y);
            acc += v1 * __int_as_float(ce1.y);
            b += 4;
        }
        if (b < end) {
            int2 ce = csr[b];
            f4 v = *reinterpret_cast<const f4*>(h1 + (size_t)ce.x * HH + l32 * 4);
            acc += v * __int_as_float(ce.y);
        }
        // cross-group reduce (lane i <-> lane i+32)
#pragma unroll
        for (int c = 0; c < 4; ++c) acc[c] += __shfl_xor(acc[c], 32, 64);
        if (grp == 0) {
            *reinterpret_cast<f4*>(h2 + (size_t)node * HH + l32 * 4) = acc;
            ssum += acc;
            ssq  += acc * acc;
        }
    }

    if (grp == 0) { ls[wid][l32] = ssum; lss[wid][l32] = ssq; }
    __syncthreads();
    if (threadIdx.x < 32) {
        int q = threadIdx.x;
        f4 st = ls[0][q] + ls[1][q] + ls[2][q] + ls[3][q];
        f4 sq = lss[0][q] + lss[1][q] + lss[2][q] + lss[3][q];
#pragma unroll
        for (int j = 0; j < 4; ++j) {
            unsafeAtomicAdd(&stats[q * 4 + j],       st[j]);
            unsafeAtomicAdd(&stats[128 + q * 4 + j], sq[j]);
        }
    }
}

// ------- final-layer BN apply + ReLU: fp32 h2 -> fp16 x5 (single rounding) -------
__global__ void k_bnapply(const float* __restrict__ h2, const float* __restrict__ scsh,
                          _Float16* __restrict__ xh) {
    int idx = blockIdx.x * 256 + threadIdx.x; // over NN*64 pairs
    if (idx >= NN * 64) return;
    int cp = idx & 63;
    float sc0 = scsh[2 * cp],       sc1 = scsh[2 * cp + 1];
    float sh0 = scsh[128 + 2 * cp], sh1 = scsh[128 + 2 * cp + 1];
    f2 v = reinterpret_cast<const f2*>(h2)[idx];
    float t0 = fmaf(v[0], sc0, sh0);
    float t1 = fmaf(v[1], sc1, sh1);
    t0 = fmaxf(t0, 0.0f);
    t1 = fmaxf(t1, 0.0f);
    h2x o;
    o[0] = (_Float16)t0;
    o[1] = (_Float16)t1;
    reinterpret_cast<h2x*>(xh)[idx] = o;
}

// ---------------- final: 16 lanes per edge, fp16 rows, fp32 math ----------------
__global__ __launch_bounds__(256) void k_final(const _Float16* __restrict__ x,
                                               const int* __restrict__ ei,
                                               const float* __restrict__ fcw,
                                               const float* __restrict__ fcb,
                                               float* __restrict__ out) {
    int gid  = blockIdx.x * 256 + threadIdx.x;
    int e    = gid >> 4;          // 16 lanes per edge
    int l16  = gid & 15;
    if (e >= NE) return;
    int a = ei[e];
    int b = ei[NE + e];
    h8 va = *reinterpret_cast<const h8*>(x + (size_t)a * HH + l16 * 8);
    h8 vb = *reinterpret_cast<const h8*>(x + (size_t)b * HH + l16 * 8);
    f4 w0 = *reinterpret_cast<const f4*>(fcw + l16 * 8);
    f4 w1 = *reinterpret_cast<const f4*>(fcw + l16 * 8 + 4);
    float p = 0.0f;
#pragma unroll
    for (int j = 0; j < 4; ++j) {
        p += (float)va[j] * (float)vb[j] * w0[j];
        p += (float)va[j + 4] * (float)vb[j + 4] * w1[j];
    }
#pragma unroll
    for (int off = 8; off > 0; off >>= 1) p += __shfl_xor(p, off, 64);
    if (l16 == 0) out[e] = 1.0f / (1.0f + expf(-(p + fcb[0])));
}

extern "C" void kernel_launch(void* const* d_in, const int* in_sizes, int n_in,
                              void* d_out, int out_size, void* d_ws, size_t ws_size,
                              hipStream_t stream) {
    const float* x   = (const float*)d_in[0];
    const void*  ei_raw = d_in[1];
    const float* cw  = (const float*)d_in[2];
    // d_in[3] = conv_b: cancels exactly through BatchNorm -> unused
    const float* gam = (const float*)d_in[4];
    const float* bet = (const float*)d_in[5];
    const float* fcw = (const float*)d_in[6];
    const float* fcb = (const float*)d_in[7];
    float* out = (float*)d_out;

    const size_t NH = (size_t)NN * HH;
    unsigned char* p = (unsigned char*)d_ws;
    float* h1 = (float*)p;       p += NH * 4;            // fp32 gemm out
    float* h2 = (float*)p;       p += NH * 4;            // fp32 aggregated
    _Float16* xh = (_Float16*)p; p += NH * 2;            // fp16 x5 for edge head
    _Float16* WtH = (_Float16*)p; p += (size_t)NL * HH * HH * 2;
    _Float16* WtL = (_Float16*)p; p += (size_t)NL * HH * HH * 2;
    int2*  csr   = (int2*)p;     p += (size_t)NE * 8;
    float* dinv  = (float*)p;    p += NN * 4;
    float* stats = (float*)p;    p += NL * 256 * 4;
    float* scsh  = (float*)p;    p += (NL + 1) * 256 * 4;
    int*   ei    = (int*)p;      p += (size_t)2 * NE * 4;
    int*   degi  = (int*)p;      p += NN * 4;
    int*   incl  = (int*)p;      p += NN * 4;
    int*   offsets = (int*)p;    p += NN * 4;
    int*   cursor  = (int*)p;    p += NN * 4;
    int*   blocksums = (int*)p;  p += NB * 4;
    int*   blockoffs = (int*)p;  p += NB * 4;
    int*   flag  = (int*)p;

    // normalize edge index dtype to int32
    k_probe<<<1, 64, 0, stream>>>((const unsigned long long*)ei_raw, flag);
    k_convert<<<(2 * NE + 255) / 256, 256, 0, stream>>>(ei_raw, flag, ei);

    // degrees -> dinv; CSR build
    k_zero<<<(NN + 255) / 256, 256, 0, stream>>>(degi, NN);
    k_zero<<<(NL * 256 + 255) / 256, 256, 0, stream>>>((int*)stats, NL * 256);
    k_count_deg<<<(NE + 255) / 256, 256, 0, stream>>>(ei + NE, degi);
    k_dinv<<<(NN + 255) / 256, 256, 0, stream>>>(degi, dinv);
    k_scan1<<<NB, 256, 0, stream>>>(degi, incl, blocksums);
    k_scan2<<<1, 512, 0, stream>>>(blocksums, blockoffs);
    k_scan3<<<NB, 256, 0, stream>>>(incl, degi, blockoffs, offsets, cursor);
    k_scatter<<<(NE + 255) / 256, 256, 0, stream>>>(ei, dinv, offsets, cursor, csr);

    // split weights (fp16 hi/lo, transposed)
    k_wt<<<(NL * HH * HH + 255) / 256, 256, 0, stream>>>(cw, WtH, WtL);

    // identity scale/shift for layer 0
    k_prep<<<1, 128, 0, stream>>>(stats, gam, bet, 0, scsh);

    for (int l = 0; l < NL; ++l) {
        k_gemm<<<(NN + 127) / 128, 256, 0, stream>>>(
            (l == 0) ? x : h2, WtH + (size_t)l * HH * HH, WtL + (size_t)l * HH * HH,
            scsh + (size_t)l * 256, (l == 0) ? 1.0f : 0.0f, h1);
        k_gather<<<GGB, 256, 0, stream>>>(h1, offsets, degi, csr, dinv, h2,
                                          stats + (size_t)l * 256);
        k_prep<<<1, 128, 0, stream>>>(stats + (size_t)l * 256, gam + (size_t)l * HH,
                                      bet + (size_t)l * HH, 1, scsh + (size_t)(l + 1) * 256);
    }
    // materialize x5 (fp16) for the edge head
    k_bnapply<<<(NN * 64 + 255) / 256, 256, 0, stream>>>(h2, scsh + (size_t)NL * 256, xh);
    k_final<<<(NE * 16 + 255) / 256, 256, 0, stream>>>(xh, ei, fcw, fcb, out);
}

// Round 7
// 923.186 us; speedup vs baseline: 1.7401x; 1.7401x over previous
//
#include <hip/hip_runtime.h>

#define NN 100000
#define NE 600000
#define HH 128
#define NL 5
#define BN_EPS 1e-5f
#define NB 391  // (NN+255)/256

typedef float f4 __attribute__((ext_vector_type(4)));
typedef float f2 __attribute__((ext_vector_type(2)));
typedef _Float16 h8 __attribute__((ext_vector_type(8)));
typedef _Float16 h2x __attribute__((ext_vector_type(2)));

// ---------------- edge-index dtype probe + normalize to int32 ----------------
__global__ void k_probe(const unsigned long long* __restrict__ e, int* __restrict__ flag) {
    if (blockIdx.x == 0 && threadIdx.x == 0) {
        int ok = 1;
        for (int i = 0; i < 64; ++i)
            if (e[i] >= (unsigned long long)NN) ok = 0;
        *flag = ok; // 1 => int64, 0 => int32
    }
}

__global__ void k_convert(const void* __restrict__ src, const int* __restrict__ flag,
                          int* __restrict__ dst) {
    int i = blockIdx.x * 256 + threadIdx.x;
    if (i >= 2 * NE) return;
    if (*flag) dst[i] = (int)((const long long*)src)[i];
    else       dst[i] = ((const int*)src)[i];
}

__global__ void k_zero(int* __restrict__ p, int n) {
    int i = blockIdx.x * 256 + threadIdx.x;
    if (i < n) p[i] = 0;
}

// ---------------- degree / dinv ----------------
__global__ void k_count_deg(const int* __restrict__ col, int* __restrict__ degi) {
    int e = blockIdx.x * 256 + threadIdx.x;
    if (e < NE) atomicAdd(&degi[col[e]], 1);
}

__global__ void k_dinv(const int* __restrict__ degi, float* __restrict__ dinv) {
    int i = blockIdx.x * 256 + threadIdx.x;
    if (i < NN) dinv[i] = rsqrtf((float)degi[i] + 1.0f);
}

// ---------------- prefix scan ----------------
__global__ __launch_bounds__(256) void k_scan1(const int* __restrict__ degi,
                                               int* __restrict__ incl,
                                               int* __restrict__ blocksums) {
    __shared__ int sd[256];
    int tid = threadIdx.x;
    int i = blockIdx.x * 256 + tid;
    int v = (i < NN) ? degi[i] : 0;
    sd[tid] = v;
    __syncthreads();
#pragma unroll
    for (int off = 1; off < 256; off <<= 1) {
        int t = (tid >= off) ? sd[tid - off] : 0;
        __syncthreads();
        sd[tid] += t;
        __syncthreads();
    }
    if (i < NN) incl[i] = sd[tid];
    if (tid == 255) blocksums[blockIdx.x] = sd[255];
}

__global__ __launch_bounds__(512) void k_scan2(const int* __restrict__ blocksums,
                                               int* __restrict__ blockoffs) {
    __shared__ int sd[512];
    int tid = threadIdx.x;
    int v = (tid < NB) ? blocksums[tid] : 0;
    sd[tid] = v;
    __syncthreads();
#pragma unroll
    for (int off = 1; off < 512; off <<= 1) {
        int t = (tid >= off) ? sd[tid - off] : 0;
        __syncthreads();
        sd[tid] += t;
        __syncthreads();
    }
    if (tid < NB) blockoffs[tid] = sd[tid] - v;
}

__global__ void k_scan3(const int* __restrict__ incl, const int* __restrict__ degi,
                        const int* __restrict__ blockoffs,
                        int* __restrict__ offsets, int* __restrict__ cursor) {
    int i = blockIdx.x * 256 + threadIdx.x;
    if (i >= NN) return;
    offsets[i] = incl[i] - degi[i] + blockoffs[blockIdx.x];
    cursor[i] = 0;
}

__global__ void k_scatter(const int* __restrict__ ei, const float* __restrict__ dinv,
                          const int* __restrict__ offsets, int* __restrict__ cursor,
                          int2* __restrict__ csr) {
    int e = blockIdx.x * 256 + threadIdx.x;
    if (e >= NE) return;
    int r = ei[e], c = ei[NE + e];
    int pos = offsets[c] + atomicAdd(&cursor[c], 1);
    int2 v;
    v.x = r;
    v.y = __float_as_int(dinv[r] * dinv[c]);
    csr[pos] = v;
}

// ---- transpose + split-cast weights: Wt{hi,lo}[l][n][k] from W[l][k][n] (fp32) ----
__global__ void k_wt(const float* __restrict__ W, _Float16* __restrict__ Wt_hi,
                     _Float16* __restrict__ Wt_lo) {
    int gid = blockIdx.x * 256 + threadIdx.x; // over NL*128*128
    if (gid >= NL * HH * HH) return;
    int l = gid >> 14;
    int rem = gid & 16383;
    int n = rem >> 7;
    int k = rem & 127;
    float w = W[l * HH * HH + k * HH + n];
    _Float16 hi = (_Float16)w;
    _Float16 lo = (_Float16)(w - (float)hi);
    Wt_hi[gid] = hi;
    Wt_lo[gid] = lo;
}

// ---- per-layer BN scale/shift: sc = gamma*rsqrt(var+eps), sh = beta-mean*sc ----
__global__ void k_prep(const float* __restrict__ stats, const float* __restrict__ gamma,
                       const float* __restrict__ beta, int mode, float* __restrict__ scsh) {
    int k = threadIdx.x; // 128 threads
    float sc = 1.0f, sh = 0.0f;
    if (mode) {
        const float inv_n = 1.0f / (float)NN;
        float mean = stats[k] * inv_n;
        float var  = stats[128 + k] * inv_n - mean * mean;
        sc = gamma[k] * rsqrtf(var + BN_EPS);
        sh = beta[k] - mean * sc;
    }
    scsh[k] = sc;
    scsh[128 + k] = sh;
}

// ---------------- fused GEMM: h1 = relu?(bn(A)) @ W, split-fp16 MFMA, fp32 I/O ------
// h1 = A_hi@W_hi + A_hi@W_lo + A_lo@W_hi  (error ~2^-22 rel; effectively fp32)
__global__ __launch_bounds__(256) void k_gemm(const float* __restrict__ A,
                                              const _Float16* __restrict__ Wt_hi,
                                              const _Float16* __restrict__ Wt_lo,
                                              const float* __restrict__ scsh,
                                              float negmul,
                                              float* __restrict__ C) {
    const int tid  = threadIdx.x;
    const int wave = tid >> 6;
    const int lane = tid & 63;
    const int r    = lane & 15;
    const int kg   = lane >> 4;        // 0..3
    const int row0 = blockIdx.x * 128 + wave * 32;

    f4 acc[2][8];
#pragma unroll
    for (int m = 0; m < 2; ++m)
#pragma unroll
        for (int n = 0; n < 8; ++n) acc[m][n] = (f4)0.0f;

    int ra0 = row0 + r;       if (ra0 >= NN) ra0 = NN - 1;
    int ra1 = row0 + 16 + r;  if (ra1 >= NN) ra1 = NN - 1;
    const float* A0 = A + (size_t)ra0 * HH + kg * 8;
    const float* A1 = A + (size_t)ra1 * HH + kg * 8;
    const _Float16* BpH = Wt_hi + (size_t)r * HH + kg * 8;  // + n*16*HH + kc*32
    const _Float16* BpL = Wt_lo + (size_t)r * HH + kg * 8;

#pragma unroll
    for (int kc = 0; kc < 4; ++kc) {
        const int k0 = kc * 32 + kg * 8;
        f4 scA = *reinterpret_cast<const f4*>(scsh + k0);
        f4 scB = *reinterpret_cast<const f4*>(scsh + k0 + 4);
        f4 shA = *reinterpret_cast<const f4*>(scsh + 128 + k0);
        f4 shB = *reinterpret_cast<const f4*>(scsh + 128 + k0 + 4);
        f4 a0x = *reinterpret_cast<const f4*>(A0 + kc * 32);
        f4 a0y = *reinterpret_cast<const f4*>(A0 + kc * 32 + 4);
        f4 a1x = *reinterpret_cast<const f4*>(A1 + kc * 32);
        f4 a1y = *reinterpret_cast<const f4*>(A1 + kc * 32 + 4);
        h8 a0hi, a0lo, a1hi, a1lo;
#pragma unroll
        for (int j = 0; j < 4; ++j) {
            float t;
            t = fmaf(a0x[j], scA[j], shA[j]); t = fmaxf(t, t * negmul);
            a0hi[j] = (_Float16)t;      a0lo[j] = (_Float16)(t - (float)a0hi[j]);
            t = fmaf(a0y[j], scB[j], shB[j]); t = fmaxf(t, t * negmul);
            a0hi[j + 4] = (_Float16)t;  a0lo[j + 4] = (_Float16)(t - (float)a0hi[j + 4]);
            t = fmaf(a1x[j], scA[j], shA[j]); t = fmaxf(t, t * negmul);
            a1hi[j] = (_Float16)t;      a1lo[j] = (_Float16)(t - (float)a1hi[j]);
            t = fmaf(a1y[j], scB[j], shB[j]); t = fmaxf(t, t * negmul);
            a1hi[j + 4] = (_Float16)t;  a1lo[j + 4] = (_Float16)(t - (float)a1hi[j + 4]);
        }
#pragma unroll
        for (int n = 0; n < 8; ++n) {
            h8 bh = *reinterpret_cast<const h8*>(BpH + (size_t)n * 16 * HH + kc * 32);
            h8 bl = *reinterpret_cast<const h8*>(BpL + (size_t)n * 16 * HH + kc * 32);
            acc[0][n] = __builtin_amdgcn_mfma_f32_16x16x32_f16(a0hi, bh, acc[0][n], 0, 0, 0);
            acc[0][n] = __builtin_amdgcn_mfma_f32_16x16x32_f16(a0hi, bl, acc[0][n], 0, 0, 0);
            acc[0][n] = __builtin_amdgcn_mfma_f32_16x16x32_f16(a0lo, bh, acc[0][n], 0, 0, 0);
            acc[1][n] = __builtin_amdgcn_mfma_f32_16x16x32_f16(a1hi, bh, acc[1][n], 0, 0, 0);
            acc[1][n] = __builtin_amdgcn_mfma_f32_16x16x32_f16(a1hi, bl, acc[1][n], 0, 0, 0);
            acc[1][n] = __builtin_amdgcn_mfma_f32_16x16x32_f16(a1lo, bh, acc[1][n], 0, 0, 0);
        }
    }

    // C/D: col=lane&15, row=(lane>>4)*4+reg  [m89-verified]
#pragma unroll
    for (int m = 0; m < 2; ++m) {
#pragma unroll
        for (int i = 0; i < 4; ++i) {
            int rr = row0 + m * 16 + kg * 4 + i;
            if (rr < NN) {
#pragma unroll
                for (int n = 0; n < 8; ++n)
                    C[(size_t)rr * HH + n * 16 + r] = acc[m][n][i];
            }
        }
    }
}

// ------- gather aggregation (fp32): one wave per node, 4-deep masked unroll -------
// Round-5 TLP (100K waves) + ILP: 4 independent row loads in flight per wave.
// Out-of-range slots read row 0 with norm 0.0 (contributes nothing, stays cached).
__global__ __launch_bounds__(256) void k_gather(const float* __restrict__ h1,
                                                const int* __restrict__ offsets,
                                                const int* __restrict__ degi,
                                                const int2* __restrict__ csr,
                                                const float* __restrict__ dinv,
                                                float* __restrict__ h2) {
    int gid  = blockIdx.x * 256 + threadIdx.x;
    int node = gid >> 6;
    int lane = gid & 63;
    if (node >= NN) return;
    float di = dinv[node];
    f2 acc0 = reinterpret_cast<const f2*>(h1 + (size_t)node * HH)[lane] * (di * di);
    f2 acc1 = (f2)0.0f, acc2 = (f2)0.0f, acc3 = (f2)0.0f;
    const int start = offsets[node];
    const int end   = start + degi[node];
    for (int b = start; b < end; b += 4) {
        int2 ce0 = csr[b];
        int2 ce1 = (b + 1 < end) ? csr[b + 1] : make_int2(0, 0);
        int2 ce2 = (b + 2 < end) ? csr[b + 2] : make_int2(0, 0);
        int2 ce3 = (b + 3 < end) ? csr[b + 3] : make_int2(0, 0);
        f2 v0 = reinterpret_cast<const f2*>(h1 + (size_t)ce0.x * HH)[lane];
        f2 v1 = reinterpret_cast<const f2*>(h1 + (size_t)ce1.x * HH)[lane];
        f2 v2 = reinterpret_cast<const f2*>(h1 + (size_t)ce2.x * HH)[lane];
        f2 v3 = reinterpret_cast<const f2*>(h1 + (size_t)ce3.x * HH)[lane];
        acc0 += v0 * __int_as_float(ce0.y);
        acc1 += v1 * __int_as_float(ce1.y);
        acc2 += v2 * __int_as_float(ce2.y);
        acc3 += v3 * __int_as_float(ce3.y);
    }
    acc0 += acc2;
    acc1 += acc3;
    acc0 += acc1;
    reinterpret_cast<f2*>(h2 + (size_t)node * HH)[lane] = acc0;
}

// ---------------- BN stats: per-column sum & sumsq (fp32) ----------------
__global__ __launch_bounds__(256) void k_bnstats(const float* __restrict__ h,
                                                 float* __restrict__ stats) {
    __shared__ f4 ls[8][32];
    __shared__ f4 lss[8][32];
    const int q  = threadIdx.x & 31;
    const int rg = threadIdx.x >> 5;
    const int r0 = blockIdx.x * 256;
    int rend = r0 + 256;
    if (rend > NN) rend = NN;
    f4 s = (f4)0.0f, ss = (f4)0.0f;
    for (int r = r0 + rg; r < rend; r += 8) {
        f4 v = *reinterpret_cast<const f4*>(h + (size_t)r * HH + q * 4);
        s += v;
        ss += v * v;
    }
    ls[rg][q] = s;
    lss[rg][q] = ss;
    __syncthreads();
    if (rg == 0) {
        f4 st = ls[0][q], sst = lss[0][q];
#pragma unroll
        for (int g = 1; g < 8; ++g) { st += ls[g][q]; sst += lss[g][q]; }
#pragma unroll
        for (int j = 0; j < 4; ++j) {
            unsafeAtomicAdd(&stats[q * 4 + j],       st[j]);
            unsafeAtomicAdd(&stats[128 + q * 4 + j], sst[j]);
        }
    }
}

// ------- final-layer BN apply + ReLU: fp32 h2 -> fp16 x5 (single rounding) -------
__global__ void k_bnapply(const float* __restrict__ h2, const float* __restrict__ scsh,
                          _Float16* __restrict__ xh) {
    int idx = blockIdx.x * 256 + threadIdx.x; // over NN*64 pairs
    if (idx >= NN * 64) return;
    int cp = idx & 63;
    float sc0 = scsh[2 * cp],       sc1 = scsh[2 * cp + 1];
    float sh0 = scsh[128 + 2 * cp], sh1 = scsh[128 + 2 * cp + 1];
    f2 v = reinterpret_cast<const f2*>(h2)[idx];
    float t0 = fmaf(v[0], sc0, sh0);
    float t1 = fmaf(v[1], sc1, sh1);
    t0 = fmaxf(t0, 0.0f);
    t1 = fmaxf(t1, 0.0f);
    h2x o;
    o[0] = (_Float16)t0;
    o[1] = (_Float16)t1;
    reinterpret_cast<h2x*>(xh)[idx] = o;
}

// ---------------- final: 16 lanes per edge, fp16 rows, fp32 math ----------------
__global__ __launch_bounds__(256) void k_final(const _Float16* __restrict__ x,
                                               const int* __restrict__ ei,
                                               const float* __restrict__ fcw,
                                               const float* __restrict__ fcb,
                                               float* __restrict__ out) {
    int gid  = blockIdx.x * 256 + threadIdx.x;
    int e    = gid >> 4;          // 16 lanes per edge
    int l16  = gid & 15;
    if (e >= NE) return;
    int a = ei[e];
    int b = ei[NE + e];
    h8 va = *reinterpret_cast<const h8*>(x + (size_t)a * HH + l16 * 8);
    h8 vb = *reinterpret_cast<const h8*>(x + (size_t)b * HH + l16 * 8);
    f4 w0 = *reinterpret_cast<const f4*>(fcw + l16 * 8);
    f4 w1 = *reinterpret_cast<const f4*>(fcw + l16 * 8 + 4);
    float p = 0.0f;
#pragma unroll
    for (int j = 0; j < 4; ++j) {
        p += (float)va[j] * (float)vb[j] * w0[j];
        p += (float)va[j + 4] * (float)vb[j + 4] * w1[j];
    }
#pragma unroll
    for (int off = 8; off > 0; off >>= 1) p += __shfl_xor(p, off, 64);
    if (l16 == 0) out[e] = 1.0f / (1.0f + expf(-(p + fcb[0])));
}

extern "C" void kernel_launch(void* const* d_in, const int* in_sizes, int n_in,
                              void* d_out, int out_size, void* d_ws, size_t ws_size,
                              hipStream_t stream) {
    const float* x   = (const float*)d_in[0];
    const void*  ei_raw = d_in[1];
    const float* cw  = (const float*)d_in[2];
    // d_in[3] = conv_b: cancels exactly through BatchNorm -> unused
    const float* gam = (const float*)d_in[4];
    const float* bet = (const float*)d_in[5];
    const float* fcw = (const float*)d_in[6];
    const float* fcb = (const float*)d_in[7];
    float* out = (float*)d_out;

    const size_t NH = (size_t)NN * HH;
    unsigned char* p = (unsigned char*)d_ws;
    float* h1 = (float*)p;       p += NH * 4;            // fp32 gemm out
    float* h2 = (float*)p;       p += NH * 4;            // fp32 aggregated
    _Float16* xh = (_Float16*)p; p += NH * 2;            // fp16 x5 for edge head
    _Float16* WtH = (_Float16*)p; p += (size_t)NL * HH * HH * 2;
    _Float16* WtL = (_Float16*)p; p += (size_t)NL * HH * HH * 2;
    int2*  csr   = (int2*)p;     p += (size_t)NE * 8;
    float* dinv  = (float*)p;    p += NN * 4;
    float* stats = (float*)p;    p += NL * 256 * 4;
    float* scsh  = (float*)p;    p += (NL + 1) * 256 * 4;
    int*   ei    = (int*)p;      p += (size_t)2 * NE * 4;
    int*   degi  = (int*)p;      p += NN * 4;
    int*   incl  = (int*)p;      p += NN * 4;
    int*   offsets = (int*)p;    p += NN * 4;
    int*   cursor  = (int*)p;    p += NN * 4;
    int*   blocksums = (int*)p;  p += NB * 4;
    int*   blockoffs = (int*)p;  p += NB * 4;
    int*   flag  = (int*)p;

    // normalize edge index dtype to int32
    k_probe<<<1, 64, 0, stream>>>((const unsigned long long*)ei_raw, flag);
    k_convert<<<(2 * NE + 255) / 256, 256, 0, stream>>>(ei_raw, flag, ei);

    // degrees -> dinv; CSR build
    k_zero<<<(NN + 255) / 256, 256, 0, stream>>>(degi, NN);
    k_zero<<<(NL * 256 + 255) / 256, 256, 0, stream>>>((int*)stats, NL * 256);
    k_count_deg<<<(NE + 255) / 256, 256, 0, stream>>>(ei + NE, degi);
    k_dinv<<<(NN + 255) / 256, 256, 0, stream>>>(degi, dinv);
    k_scan1<<<NB, 256, 0, stream>>>(degi, incl, blocksums);
    k_scan2<<<1, 512, 0, stream>>>(blocksums, blockoffs);
    k_scan3<<<NB, 256, 0, stream>>>(incl, degi, blockoffs, offsets, cursor);
    k_scatter<<<(NE + 255) / 256, 256, 0, stream>>>(ei, dinv, offsets, cursor, csr);

    // split weights (fp16 hi/lo, transposed)
    k_wt<<<(NL * HH * HH + 255) / 256, 256, 0, stream>>>(cw, WtH, WtL);

    // identity scale/shift for layer 0
    k_prep<<<1, 128, 0, stream>>>(stats, gam, bet, 0, scsh);

    for (int l = 0; l < NL; ++l) {
        k_gemm<<<(NN + 127) / 128, 256, 0, stream>>>(
            (l == 0) ? x : h2, WtH + (size_t)l * HH * HH, WtL + (size_t)l * HH * HH,
            scsh + (size_t)l * 256, (l == 0) ? 1.0f : 0.0f, h1);
        k_gather<<<(NN * 64 + 255) / 256, 256, 0, stream>>>(h1, offsets, degi, csr, dinv, h2);
        k_bnstats<<<NB, 256, 0, stream>>>(h2, stats + (size_t)l * 256);
        k_prep<<<1, 128, 0, stream>>>(stats + (size_t)l * 256, gam + (size_t)l * HH,
                                      bet + (size_t)l * HH, 1, scsh + (size_t)(l + 1) * 256);
    }
    // materialize x5 (fp16) for the edge head
    k_bnapply<<<(NN * 64 + 255) / 256, 256, 0, stream>>>(h2, scsh + (size_t)NL * 256, xh);
    k_final<<<(NE * 16 + 255) / 256, 256, 0, stream>>>(xh, ei, fcw, fcb, out);
}